// Round 10
// baseline (81.006 us; speedup 1.0000x reference)
//
#include <hip/hip_runtime.h>
#include <hip/hip_bf16.h>

#define Nn 8192
#define Mm 1024
#define Dd 1024

typedef __attribute__((ext_vector_type(8))) short short8;
typedef __attribute__((ext_vector_type(4))) short short4v;
typedef __attribute__((ext_vector_type(4))) float f32x4;
typedef __attribute__((ext_vector_type(4))) unsigned uint4v;

typedef const __attribute__((address_space(1))) void* gas_p;
typedef __attribute__((address_space(3))) void* las_p;

// round-to-nearest-even fp32 -> bf16 (bit pattern as short)
__device__ __forceinline__ short f2bf(float f) {
  unsigned u = __builtin_bit_cast(unsigned, f);
  u += 0x7fffu + ((u >> 16) & 1u);
  return (short)(u >> 16);
}

// packed RNE fp32x2 -> bf16x2 (hardware cvt)
__device__ __forceinline__ unsigned cvt2bf(float lo, float hi) {
  unsigned r;
  asm("v_cvt_pk_bf16_f32 %0, %1, %2" : "=v"(r) : "v"(lo), "v"(hi));
  return r;
}

// 8 fp32 -> short8 of bf16 (R5/R6-proven)
__device__ __forceinline__ short8 cvt8(float4 a, float4 b) {
  uint4v q;
  q[0] = cvt2bf(a.x, a.y);
  q[1] = cvt2bf(a.z, a.w);
  q[2] = cvt2bf(b.x, b.y);
  q[3] = cvt2bf(b.z, b.w);
  return __builtin_bit_cast(short8, q);
}

// ---------------- kernel 1: B'[m,d] = bf16(u*w3 + w1); c[m] = u . w2 ----------------
__global__ void prep_b_kernel(const float* __restrict__ u, const float* __restrict__ w,
                              short* __restrict__ Bp, float* __restrict__ cvec) {
  int m = blockIdx.x;      // 1024 blocks
  int t = threadIdx.x;     // 256 threads, 4 elems each
  float4 uv = ((const float4*)(u + (size_t)m * Dd))[t];
  float4 w1 = ((const float4*)(w))[t];
  float4 w2 = ((const float4*)(w + Dd))[t];
  float4 w3 = ((const float4*)(w + 2 * Dd))[t];
  float p = uv.x * w2.x + uv.y * w2.y + uv.z * w2.z + uv.w * w2.w;
  short4v o;
  o[0] = f2bf(fmaf(uv.x, w3.x, w1.x));
  o[1] = f2bf(fmaf(uv.y, w3.y, w1.y));
  o[2] = f2bf(fmaf(uv.z, w3.z, w1.z));
  o[3] = f2bf(fmaf(uv.w, w3.w, w1.w));
  *(short4v*)(Bp + (size_t)m * Dd + t * 4) = o;

#pragma unroll
  for (int off = 32; off > 0; off >>= 1) p += __shfl_down(p, off);
  __shared__ float sred[4];
  if ((t & 63) == 0) sred[t >> 6] = p;
  __syncthreads();
  if (t == 0) cvec[m] = sred[0] + sred[1] + sred[2] + sred[3];
}

// ---------------- kernel 2: B-resident GEMM  S = bf16(h) @ B'^T + c ----------------
// Block 256 rows x 64 cols, 512 thr = 8 waves (8M x 1N), wave = 32 rows x 64 cols.
// B' block-panel (64 cols x full K=1024) lives in LDS as 16 panels of [64][64]
// bf16 (8 KB each, 128 KB total), staged ONCE via the R0/R1-PROVEN
// global_load_lds pattern (8 rows x 128B per call, kc=(lane&7)^l8 pre-swizzle).
// ONE __syncthreads total; then 32 K32-steps free-run (LDS is read-only).
// A: fp32 direct from global (R5/R6-proven float4-pair + cvt8 fragments),
// X/Y depth-2 register pipeline. Fragment reads/epilogue: R0/R7-proven math.
// Zero A-row duplication (8M x 1N) keeps per-XCD L2 traffic ~4 MB/pass.
__global__ __launch_bounds__(512) void gemm_bres_kernel(
    const float* __restrict__ h,   // N x D fp32
    const short* __restrict__ B,   // M x D bf16 (B')
    const float* __restrict__ cvec,// M
    float* __restrict__ out)       // N x M fp32
{
  __shared__ __align__(16) short Bs[16][64 * 64];  // 128 KB

  const int bid = blockIdx.x;     // 512 blocks = 32 brow x 16 bcol
  // XCD map: xcd gets brows [xcd*4, xcd*4+4) x all 16 bcols (A panels L2-shared)
  const int xcd = bid & 7;
  const int idx = bid >> 3;       // 0..63
  const int brow = xcd * 4 + (idx >> 4);  // 0..31
  const int bcol = idx & 15;              // 0..15

  const int tid  = threadIdx.x;
  const int lane = tid & 63;
  const int wid  = tid >> 6;      // 0..7

  // ---- stage B panel (R0-proven pattern): wave w stages panels 2w, 2w+1 ----
  const int l8 = lane >> 3;                // row within 8-row group
  const int kc = (lane & 7) ^ l8;          // pre-swizzled 16B-chunk index
  {
#pragma unroll
    for (int pi = 0; pi < 2; ++pi) {
      const int p = wid * 2 + pi;          // panel = K-tile index 0..15
#pragma unroll
      for (int j = 0; j < 8; ++j) {
        const short* src = B + (size_t)(bcol * 64 + j * 8 + l8) * Dd + p * 64 + kc * 8;
        __builtin_amdgcn_global_load_lds((gas_p)src, (las_p)&Bs[p][(j * 8) * 64], 16, 0, 0);
      }
    }
  }
  __syncthreads();   // drains vmcnt(0): whole B panel staged; LDS read-only after

  // ---- A fragment pointers (R5-proven form) ----
  const int lr = lane & 15;
  const int lk = lane >> 4;                // 0..3
  const float* Ab = h + (size_t)(brow * 256 + wid * 32 + lr) * Dd + lk * 8;

  // ---- fragment read constants (R0-proven form) ----
  const int kb = lk * 16;                  // byte offset of 16B chunk in 64B k-slice
  const int sw = (lane & 7) << 4;          // read-side XOR (row&7)<<4

  f32x4 acc[2][4] = {};

  float4 aX0, aX1, aX2, aX3;   // rows wid*32+lr, wid*32+16+lr : 8 floats each
  float4 aY0, aY1, aY2, aY3;

#define LOAD_A(s, a0, a1, a2, a3) do { \
    const float* ap_ = Ab + (s) * 32; \
    a0 = *(const float4*)(ap_); \
    a1 = *(const float4*)(ap_ + 4); \
    a2 = *(const float4*)(ap_ + 16 * Dd); \
    a3 = *(const float4*)(ap_ + 16 * Dd + 4); \
  } while (0)

#define COMPUTE(s, a0, a1, a2, a3) do { \
    const short8 af0_ = cvt8(a0, a1); \
    const short8 af1_ = cvt8(a2, a3); \
    const char* bp_ = (const char*)&Bs[(s) >> 1][0]; \
    const int koff_ = (((s) & 1) * 64 + kb); \
    _Pragma("unroll") \
    for (int j = 0; j < 4; ++j) { \
      const short8 bfr_ = *(const short8*)(bp_ + ((j * 16 + lr) * 128 + (koff_ ^ sw))); \
      acc[0][j] = __builtin_amdgcn_mfma_f32_16x16x32_bf16(af0_, bfr_, acc[0][j], 0, 0, 0); \
      acc[1][j] = __builtin_amdgcn_mfma_f32_16x16x32_bf16(af1_, bfr_, acc[1][j], 0, 0, 0); \
    } \
  } while (0)

  // 32 K32-steps, X/Y depth-2 register pipeline (R5-proven shape)
  LOAD_A(0, aX0, aX1, aX2, aX3);
#pragma unroll 1
  for (int s = 0; s < 30; s += 2) {
    LOAD_A(s + 1, aY0, aY1, aY2, aY3);
    COMPUTE(s, aX0, aX1, aX2, aX3);
    LOAD_A(s + 2, aX0, aX1, aX2, aX3);
    COMPUTE(s + 1, aY0, aY1, aY2, aY3);
  }
  LOAD_A(31, aY0, aY1, aY2, aY3);
  COMPUTE(30, aX0, aX1, aX2, aX3);
  COMPUTE(31, aY0, aY1, aY2, aY3);
#undef LOAD_A
#undef COMPUTE

  // --- epilogue: S[n,m] = acc + c[m] (R7-proven C/D mapping) ---
  const int n0 = brow * 256 + wid * 32 + lk * 4;
  const int m0 = bcol * 64 + lr;
#pragma unroll
  for (int j = 0; j < 4; ++j) {
    const float cm = cvec[m0 + j * 16];
#pragma unroll
    for (int i = 0; i < 2; ++i) {
      float* op = out + (size_t)(n0 + i * 16) * Mm + m0 + j * 16;
#pragma unroll
      for (int r = 0; r < 4; ++r)
        op[(size_t)r * Mm] = acc[i][j][r] + cm;
    }
  }
}

extern "C" void kernel_launch(void* const* d_in, const int* in_sizes, int n_in,
                              void* d_out, int out_size, void* d_ws, size_t ws_size,
                              hipStream_t stream) {
  const float* h = (const float*)d_in[0];
  const float* u = (const float*)d_in[1];
  const float* w = (const float*)d_in[2];
  float* out = (float*)d_out;

  // workspace layout: B' bf16 (2MB) | c fp32 (4KB)
  short* Bp  = (short*)d_ws;
  float* cvec = (float*)(Bp + (size_t)Mm * Dd);

  prep_b_kernel<<<Mm, 256, 0, stream>>>(u, w, Bp, cvec);
  gemm_bres_kernel<<<(Nn / 256) * (Mm / 64), 512, 0, stream>>>(h, Bp, cvec, out);
}

// Round 11
// 47.148 us; speedup vs baseline: 1.7181x; 1.7181x over previous
//
#include <hip/hip_runtime.h>
#include <hip/hip_bf16.h>

#define Nn 8192
#define Mm 1024
#define Dd 1024

typedef __attribute__((ext_vector_type(8))) short short8;
typedef __attribute__((ext_vector_type(4))) short short4v;
typedef __attribute__((ext_vector_type(4))) float f32x4;

typedef const __attribute__((address_space(1))) void* gas_p;
typedef __attribute__((address_space(3))) void* las_p;

// round-to-nearest-even fp32 -> bf16 (bit pattern as short)
__device__ __forceinline__ short f2bf(float f) {
  unsigned u = __builtin_bit_cast(unsigned, f);
  u += 0x7fffu + ((u >> 16) & 1u);
  return (short)(u >> 16);
}

// ---------------- kernel 1: h (fp32) -> A (bf16)  [R1-passed] ----------------
__global__ void conv_h_kernel(const float* __restrict__ h, short* __restrict__ A) {
  long i = (long)blockIdx.x * blockDim.x + threadIdx.x; // 8 elems per thread
  const float4* h4 = (const float4*)h;
  float4 a = h4[2 * i];
  float4 b = h4[2 * i + 1];
  short8 o;
  o[0] = f2bf(a.x); o[1] = f2bf(a.y); o[2] = f2bf(a.z); o[3] = f2bf(a.w);
  o[4] = f2bf(b.x); o[5] = f2bf(b.y); o[6] = f2bf(b.z); o[7] = f2bf(b.w);
  *(short8*)(A + 8 * i) = o;
}

// ---------------- kernel 2: B'[m,d] = bf16(u*w3 + w1); c[m] = u . w2  [R1-passed] ----------------
__global__ void prep_b_kernel(const float* __restrict__ u, const float* __restrict__ w,
                              short* __restrict__ Bp, float* __restrict__ cvec) {
  int m = blockIdx.x;      // 1024 blocks
  int t = threadIdx.x;     // 256 threads, 4 elems each
  float4 uv = ((const float4*)(u + (size_t)m * Dd))[t];
  float4 w1 = ((const float4*)(w))[t];
  float4 w2 = ((const float4*)(w + Dd))[t];
  float4 w3 = ((const float4*)(w + 2 * Dd))[t];
  float p = uv.x * w2.x + uv.y * w2.y + uv.z * w2.z + uv.w * w2.w;
  short4v o;
  o[0] = f2bf(fmaf(uv.x, w3.x, w1.x));
  o[1] = f2bf(fmaf(uv.y, w3.y, w1.y));
  o[2] = f2bf(fmaf(uv.z, w3.z, w1.z));
  o[3] = f2bf(fmaf(uv.w, w3.w, w1.w));
  *(short4v*)(Bp + (size_t)m * Dd + t * 4) = o;

#pragma unroll
  for (int off = 32; off > 0; off >>= 1) p += __shfl_down(p, off);
  __shared__ float sred[4];
  if ((t & 63) == 0) sred[t >> 6] = p;
  __syncthreads();
  if (t == 0) cvec[m] = sred[0] + sred[1] + sred[2] + sred[3];
}

// ---------------- kernel 3: GEMM  S = A @ B'^T + c  (m201-style 2-phase/K-tile) ----------------
// Tile 128x256, BK=64, 512 thr = 8 waves (2M x 4N), wave 64x64 out.
// TRIPLE-buffered LDS (A 16K + B 32K)x3 = 144 KB -> boundary s_waitcnt vmcnt(6)
// NEVER drains to 0 in the main loop (tile kt+2 stays in flight across barriers).
// Per K-tile: 2 phases, each {8 ds_read_b128 -> s_barrier -> lgkmcnt(0) ->
// setprio(1) 16 MFMA setprio(0) -> s_barrier} -- 1:8 barrier:MFMA (m201 ratio).
// All staging (gload_lds, 8 rows x 128B, kc=(lane&7)^l8 pre-swizzle), fragment
// reads ((row)*128 + koff^sw) and epilogue are byte-identical to R0/R1-passed code.
__global__ __launch_bounds__(512) void gemm_kernel(
    const short* __restrict__ A,   // N x D bf16
    const short* __restrict__ B,   // M x D bf16 (B')
    const float* __restrict__ cvec,// M
    float* __restrict__ out)       // N x M fp32
{
  __shared__ __align__(16) short As[3][128 * 64];  // 48 KB
  __shared__ __align__(16) short Bs[3][256 * 64];  // 96 KB

  const int bid = blockIdx.x;
  // bijective XCD swizzle: 256 blocks, 32 per XCD; each XCD: 8 brows x all 4 bcols
  const int swz  = (bid & 7) * 32 + (bid >> 3);
  const int brow = swz >> 2;   // 0..63  (128-row panel)
  const int bcol = swz & 3;    // 0..3   (256-col panel)

  const int tid  = threadIdx.x;
  const int lane = tid & 63;
  const int wid  = tid >> 6;   // 0..7

  // --- staging (R0-proven pattern): wave stages A rows [wid*16,+16), B rows [wid*32,+32) ---
  const int l8 = lane >> 3;                // row within 8-row group
  const int kc = (lane & 7) ^ l8;          // pre-swizzled 16B-chunk index
  const short* Ag = A + (size_t)(brow * 128 + wid * 16 + l8) * Dd + kc * 8;
  const short* Bg = B + (size_t)(bcol * 256 + wid * 32 + l8) * Dd + kc * 8;
  const int AsOff = (wid * 16) * 64;
  const int BsOff = (wid * 32) * 64;

#define STAGE(buf, kt) do { \
    const short* Agk_ = Ag + (size_t)(kt) * 64; \
    const short* Bgk_ = Bg + (size_t)(kt) * 64; \
    __builtin_amdgcn_global_load_lds((gas_p)(Agk_),          (las_p)(&As[buf][AsOff]),           16, 0, 0); \
    __builtin_amdgcn_global_load_lds((gas_p)(Agk_ + 8 * Dd), (las_p)(&As[buf][AsOff + 8 * 64]),  16, 0, 0); \
    __builtin_amdgcn_global_load_lds((gas_p)(Bgk_),           (las_p)(&Bs[buf][BsOff]),          16, 0, 0); \
    __builtin_amdgcn_global_load_lds((gas_p)(Bgk_ +  8 * Dd), (las_p)(&Bs[buf][BsOff +  8*64]),  16, 0, 0); \
    __builtin_amdgcn_global_load_lds((gas_p)(Bgk_ + 16 * Dd), (las_p)(&Bs[buf][BsOff + 16*64]),  16, 0, 0); \
    __builtin_amdgcn_global_load_lds((gas_p)(Bgk_ + 24 * Dd), (las_p)(&Bs[buf][BsOff + 24*64]),  16, 0, 0); \
  } while (0)

  // --- fragment reads (R0-proven math): 8 waves as 2M x 4N, wave 64x64 ---
  const int wr = wid >> 2;                 // 0..1
  const int wc = wid & 3;                  // 0..3
  const int arow0 = wr * 64 + (lane & 15);
  const int brow0 = wc * 64 + (lane & 15);
  const int kb = (lane >> 4) * 16;         // 16B chunk within 64B k-slice
  const int sw = (lane & 7) << 4;          // read-side XOR (row&7)<<4

  f32x4 acc[4][4] = {};

  // one phase: 8 ds_read -> BAR -> lgkm0 -> prio1 16xMFMA prio0  (caller adds closing sync)
#define PHASE(buf, kk) do { \
    const char* A_ = (const char*)&As[buf][0]; \
    const char* B_ = (const char*)&Bs[buf][0]; \
    const int ko_ = (kk) * 64 + kb; \
    short8 a0 = *(const short8*)(A_ + ((arow0 +  0) * 128 + (ko_ ^ sw))); \
    short8 a1 = *(const short8*)(A_ + ((arow0 + 16) * 128 + (ko_ ^ sw))); \
    short8 a2 = *(const short8*)(A_ + ((arow0 + 32) * 128 + (ko_ ^ sw))); \
    short8 a3 = *(const short8*)(A_ + ((arow0 + 48) * 128 + (ko_ ^ sw))); \
    short8 b0 = *(const short8*)(B_ + ((brow0 +  0) * 128 + (ko_ ^ sw))); \
    short8 b1 = *(const short8*)(B_ + ((brow0 + 16) * 128 + (ko_ ^ sw))); \
    short8 b2 = *(const short8*)(B_ + ((brow0 + 32) * 128 + (ko_ ^ sw))); \
    short8 b3 = *(const short8*)(B_ + ((brow0 + 48) * 128 + (ko_ ^ sw))); \
    __builtin_amdgcn_s_barrier(); \
    asm volatile("s_waitcnt lgkmcnt(0)" ::: "memory"); \
    __builtin_amdgcn_sched_barrier(0); \
    __builtin_amdgcn_s_setprio(1); \
    acc[0][0] = __builtin_amdgcn_mfma_f32_16x16x32_bf16(a0, b0, acc[0][0], 0, 0, 0); \
    acc[0][1] = __builtin_amdgcn_mfma_f32_16x16x32_bf16(a0, b1, acc[0][1], 0, 0, 0); \
    acc[0][2] = __builtin_amdgcn_mfma_f32_16x16x32_bf16(a0, b2, acc[0][2], 0, 0, 0); \
    acc[0][3] = __builtin_amdgcn_mfma_f32_16x16x32_bf16(a0, b3, acc[0][3], 0, 0, 0); \
    acc[1][0] = __builtin_amdgcn_mfma_f32_16x16x32_bf16(a1, b0, acc[1][0], 0, 0, 0); \
    acc[1][1] = __builtin_amdgcn_mfma_f32_16x16x32_bf16(a1, b1, acc[1][1], 0, 0, 0); \
    acc[1][2] = __builtin_amdgcn_mfma_f32_16x16x32_bf16(a1, b2, acc[1][2], 0, 0, 0); \
    acc[1][3] = __builtin_amdgcn_mfma_f32_16x16x32_bf16(a1, b3, acc[1][3], 0, 0, 0); \
    acc[2][0] = __builtin_amdgcn_mfma_f32_16x16x32_bf16(a2, b0, acc[2][0], 0, 0, 0); \
    acc[2][1] = __builtin_amdgcn_mfma_f32_16x16x32_bf16(a2, b1, acc[2][1], 0, 0, 0); \
    acc[2][2] = __builtin_amdgcn_mfma_f32_16x16x32_bf16(a2, b2, acc[2][2], 0, 0, 0); \
    acc[2][3] = __builtin_amdgcn_mfma_f32_16x16x32_bf16(a2, b3, acc[2][3], 0, 0, 0); \
    acc[3][0] = __builtin_amdgcn_mfma_f32_16x16x32_bf16(a3, b0, acc[3][0], 0, 0, 0); \
    acc[3][1] = __builtin_amdgcn_mfma_f32_16x16x32_bf16(a3, b1, acc[3][1], 0, 0, 0); \
    acc[3][2] = __builtin_amdgcn_mfma_f32_16x16x32_bf16(a3, b2, acc[3][2], 0, 0, 0); \
    acc[3][3] = __builtin_amdgcn_mfma_f32_16x16x32_bf16(a3, b3, acc[3][3], 0, 0, 0); \
    __builtin_amdgcn_s_setprio(0); \
  } while (0)

  const int NT = Dd / 64;  // 16 K-tiles

  // prologue: t0 -> buf0, t1 -> buf1 (12 loads/thread out); t0 complete at vmcnt(6)
  STAGE(0, 0);
  STAGE(1, 1);
  asm volatile("s_waitcnt vmcnt(6)" ::: "memory");
  __builtin_amdgcn_s_barrier();

#pragma unroll 1
  for (int kt = 0; kt < NT; ++kt) {
    const int cb = kt % 3;
    // phase 0: frags(kk=0) + stage tile kt+2 into buf[(kt+2)%3] (last read in iter kt-1)
    {
      if (kt + 2 < NT) STAGE((kt + 2) % 3, kt + 2);
      PHASE(cb, 0);
      __builtin_amdgcn_s_barrier();
    }
    // phase 1: frags(kk=1)
    {
      PHASE(cb, 1);
      // boundary: tile kt+1 must be resident before next iter's ds_reads
      if (kt < NT - 2)       asm volatile("s_waitcnt vmcnt(6)" ::: "memory");
      else if (kt == NT - 2) asm volatile("s_waitcnt vmcnt(0)" ::: "memory");
      if (kt < NT - 1) __builtin_amdgcn_s_barrier();
    }
  }
#undef STAGE
#undef PHASE

  // --- epilogue: S[n,m] = acc + c[m] (R0-proven C/D mapping) ---
  const int n0 = brow * 128 + wr * 64 + (lane >> 4) * 4;
  const int m0 = bcol * 256 + wc * 64 + (lane & 15);
#pragma unroll
  for (int j = 0; j < 4; ++j) {
    const float cm = cvec[m0 + j * 16];
#pragma unroll
    for (int i = 0; i < 4; ++i) {
      float* op = out + (size_t)(n0 + i * 16) * Mm + m0 + j * 16;
#pragma unroll
      for (int r = 0; r < 4; ++r)
        op[(size_t)r * Mm] = acc[i][j][r] + cm;
    }
  }
}

extern "C" void kernel_launch(void* const* d_in, const int* in_sizes, int n_in,
                              void* d_out, int out_size, void* d_ws, size_t ws_size,
                              hipStream_t stream) {
  const float* h = (const float*)d_in[0];
  const float* u = (const float*)d_in[1];
  const float* w = (const float*)d_in[2];
  float* out = (float*)d_out;

  // workspace layout: A bf16 (16MB) | B' bf16 (2MB) | c fp32 (4KB)
  short* Abf = (short*)d_ws;
  short* Bp  = Abf + (size_t)Nn * Dd;
  float* cvec = (float*)(Bp + (size_t)Mm * Dd);

  conv_h_kernel<<<(Nn * Dd / 8) / 256, 256, 0, stream>>>(h, Abf);
  prep_b_kernel<<<Mm, 256, 0, stream>>>(u, w, Bp, cvec);
  gemm_kernel<<<(Nn / 128) * (Mm / 256), 512, 0, stream>>>(Abf, Bp, cvec, out);
}

// Round 12
// 39.234 us; speedup vs baseline: 2.0647x; 1.2017x over previous
//
#include <hip/hip_runtime.h>
#include <hip/hip_bf16.h>

#define Nn 8192
#define Mm 1024
#define Dd 1024

typedef __attribute__((ext_vector_type(8))) short short8;
typedef __attribute__((ext_vector_type(4))) short short4v;
typedef __attribute__((ext_vector_type(4))) float f32x4;
typedef __attribute__((ext_vector_type(4))) unsigned uint4v;

typedef const __attribute__((address_space(1))) void* gas_p;
typedef __attribute__((address_space(3))) void* las_p;

// round-to-nearest-even fp32 -> bf16 (bit pattern as short)
__device__ __forceinline__ short f2bf(float f) {
  unsigned u = __builtin_bit_cast(unsigned, f);
  u += 0x7fffu + ((u >> 16) & 1u);
  return (short)(u >> 16);
}

// packed RNE fp32x2 -> bf16x2 (hardware cvt)
__device__ __forceinline__ unsigned cvt2bf(float lo, float hi) {
  unsigned r;
  asm("v_cvt_pk_bf16_f32 %0, %1, %2" : "=v"(r) : "v"(lo), "v"(hi));
  return r;
}

// ---------------- kernel 1: B'[m,d] = bf16(u*w3 + w1); c[m] = u . w2  [R1-passed] ----------------
__global__ void prep_b_kernel(const float* __restrict__ u, const float* __restrict__ w,
                              short* __restrict__ Bp, float* __restrict__ cvec) {
  int m = blockIdx.x;      // 1024 blocks
  int t = threadIdx.x;     // 256 threads, 4 elems each
  float4 uv = ((const float4*)(u + (size_t)m * Dd))[t];
  float4 w1 = ((const float4*)(w))[t];
  float4 w2 = ((const float4*)(w + Dd))[t];
  float4 w3 = ((const float4*)(w + 2 * Dd))[t];
  float p = uv.x * w2.x + uv.y * w2.y + uv.z * w2.z + uv.w * w2.w;
  short4v o;
  o[0] = f2bf(fmaf(uv.x, w3.x, w1.x));
  o[1] = f2bf(fmaf(uv.y, w3.y, w1.y));
  o[2] = f2bf(fmaf(uv.z, w3.z, w1.z));
  o[3] = f2bf(fmaf(uv.w, w3.w, w1.w));
  *(short4v*)(Bp + (size_t)m * Dd + t * 4) = o;

#pragma unroll
  for (int off = 32; off > 0; off >>= 1) p += __shfl_down(p, off);
  __shared__ float sred[4];
  if ((t & 63) == 0) sred[t >> 6] = p;
  __syncthreads();
  if (t == 0) cvec[m] = sred[0] + sred[1] + sred[2] + sred[3];
}

// ---------------- kernel 2: fused GEMM  S = bf16(h) @ B'^T + c ----------------
// R7-passed structure (128x128 tile, BK=64, 512 thr = 8 waves 2Mx4N, wave 64x32;
// A fp32->regs->cvt->swizzled ds_write; B gload_lds pre-swizzled) with the ONE
// change R5/R7 lacked: B TRIPLE-buffered (Bs[3] 48KB + As[2] 32KB = 80KB -> still
// 2 blocks/CU), staged 2-ahead -> boundary wait is s_waitcnt vmcnt(2), which
// NEVER drains to 0 in the main loop (B(kt+2) stays in flight across barriers,
// T4/m218). 2 phases/tile, each {6 ds_read -> BAR -> lgkm0+sched0 -> prio1
// 8xMFMA prio0 -> BAR} (m201 discipline).
// Queue trace (steady iter kt): carried B(kt+1)2 + issued A(kt+1)4 + B(kt+2)2;
// WRITE_A's implicit in-order vmem wait retires A(kt+1) AND B(kt+1); explicit
// vmcnt(2) leaves exactly B(kt+2). Tail kt=NT-2: vmcnt(0). Buffer overwrite
// safety: Bs[(kt+2)%3] / As[(kt+1)&1] last read in iter kt-1, retired at that
// iter's closing barrier.
__global__ __launch_bounds__(512, 2) void gemm_fused_kernel(
    const float* __restrict__ h,   // N x D fp32
    const short* __restrict__ B,   // M x D bf16 (B')
    const float* __restrict__ cvec,// M
    float* __restrict__ out)       // N x M fp32
{
  __shared__ __align__(16) short As[2][128 * 64];  // 32 KB
  __shared__ __align__(16) short Bs[3][128 * 64];  // 48 KB

  const int bid = blockIdx.x;
  // bijective XCD swizzle: 512 blocks, 64 per XCD; M-dim fastest within XCD
  const int swz  = (bid & 7) * 64 + (bid >> 3);
  const int brow = swz >> 3;   // 0..63
  const int bcol = swz & 7;    // 0..7

  const int tid  = threadIdx.x;
  const int lane = tid & 63;
  const int wid  = tid >> 6;   // 0..7

  // --- B staging (R7-passed): wave stages 16 rows, 2 gload_lds calls ---
  const int l8 = lane >> 3;
  const int kc = (lane & 7) ^ l8;           // pre-swizzled 16B-chunk index
  const short* Bg = B + (size_t)(bcol * 128 + wid * 16 + l8) * Dd + kc * 8;
  const int BsOff = (wid * 16) * 64;

  // --- A reg-staging (R7-passed): thread t -> row t>>2, 16-float k-group t&3 ---
  const int arow = tid >> 2;
  const int akq  = tid & 3;
  const float* hg = h + (size_t)(brow * 128 + arow) * Dd + akq * 16;
  const int asw  = (arow & 7) << 4;
  const int abyte0 = arow * 128 + ((akq * 32) ^ asw);
  const int abyte1 = arow * 128 + ((akq * 32 + 16) ^ asw);

  // --- fragment reads (R7-passed): 8 waves as 2M x 4N, wave 64x32 ---
  const int wr = wid >> 2;                 // 0..1
  const int wc = wid & 3;                  // 0..3
  const int arow0 = wr * 64 + (lane & 15);
  const int brow0 = wc * 32 + (lane & 15);
  const int kb = (lane >> 4) * 16;
  const int sw = (lane & 7) << 4;

  f32x4 acc[4][2] = {};
  float4 av0, av1, av2, av3;
  const int NT = Dd / 64;  // 16 K-tiles

#define STAGE_B(buf, kt) do { \
    const short* Bgk_ = Bg + (size_t)(kt) * 64; \
    __builtin_amdgcn_global_load_lds((gas_p)(Bgk_),          (las_p)(&Bs[buf][BsOff]),          16, 0, 0); \
    __builtin_amdgcn_global_load_lds((gas_p)(Bgk_ + 8 * Dd), (las_p)(&Bs[buf][BsOff + 8 * 64]), 16, 0, 0); \
  } while (0)

#define LOAD_A(kt) do { \
    const float* ab_ = hg + (size_t)(kt) * 64; \
    av0 = *(const float4*)(ab_); \
    av1 = *(const float4*)(ab_ + 4); \
    av2 = *(const float4*)(ab_ + 8); \
    av3 = *(const float4*)(ab_ + 12); \
  } while (0)

#define WRITE_A(buf) do { \
    uint4v q_; \
    q_[0] = cvt2bf(av0.x, av0.y); q_[1] = cvt2bf(av0.z, av0.w); \
    q_[2] = cvt2bf(av1.x, av1.y); q_[3] = cvt2bf(av1.z, av1.w); \
    *(uint4v*)((char*)&As[buf][0] + abyte0) = q_; \
    q_[0] = cvt2bf(av2.x, av2.y); q_[1] = cvt2bf(av2.z, av2.w); \
    q_[2] = cvt2bf(av3.x, av3.y); q_[3] = cvt2bf(av3.z, av3.w); \
    *(uint4v*)((char*)&As[buf][0] + abyte1) = q_; \
  } while (0)

// one phase: 6 ds_read -> (staging issues) -> BAR -> lgkm0+sched0 -> prio1 8xMFMA prio0 -> BAR
#define PHASE(bufA, bufB, kk, ...) do { \
    const char* A_ = (const char*)&As[bufA][0]; \
    const char* B_ = (const char*)&Bs[bufB][0]; \
    const int ko_ = (kk) * 64 + kb; \
    short8 a0 = *(const short8*)(A_ + ((arow0 +  0) * 128 + (ko_ ^ sw))); \
    short8 a1 = *(const short8*)(A_ + ((arow0 + 16) * 128 + (ko_ ^ sw))); \
    short8 a2 = *(const short8*)(A_ + ((arow0 + 32) * 128 + (ko_ ^ sw))); \
    short8 a3 = *(const short8*)(A_ + ((arow0 + 48) * 128 + (ko_ ^ sw))); \
    short8 b0 = *(const short8*)(B_ + ((brow0 +  0) * 128 + (ko_ ^ sw))); \
    short8 b1 = *(const short8*)(B_ + ((brow0 + 16) * 128 + (ko_ ^ sw))); \
    __VA_ARGS__; \
    __builtin_amdgcn_s_barrier(); \
    asm volatile("s_waitcnt lgkmcnt(0)" ::: "memory"); \
    __builtin_amdgcn_sched_barrier(0); \
    __builtin_amdgcn_s_setprio(1); \
    acc[0][0] = __builtin_amdgcn_mfma_f32_16x16x32_bf16(a0, b0, acc[0][0], 0, 0, 0); \
    acc[0][1] = __builtin_amdgcn_mfma_f32_16x16x32_bf16(a0, b1, acc[0][1], 0, 0, 0); \
    acc[1][0] = __builtin_amdgcn_mfma_f32_16x16x32_bf16(a1, b0, acc[1][0], 0, 0, 0); \
    acc[1][1] = __builtin_amdgcn_mfma_f32_16x16x32_bf16(a1, b1, acc[1][1], 0, 0, 0); \
    acc[2][0] = __builtin_amdgcn_mfma_f32_16x16x32_bf16(a2, b0, acc[2][0], 0, 0, 0); \
    acc[2][1] = __builtin_amdgcn_mfma_f32_16x16x32_bf16(a2, b1, acc[2][1], 0, 0, 0); \
    acc[3][0] = __builtin_amdgcn_mfma_f32_16x16x32_bf16(a3, b0, acc[3][0], 0, 0, 0); \
    acc[3][1] = __builtin_amdgcn_mfma_f32_16x16x32_bf16(a3, b1, acc[3][1], 0, 0, 0); \
    __builtin_amdgcn_s_setprio(0); \
  } while (0)

  // ---- prologue: A(0)->As[0]; B(0)->Bs[0]; B(1)->Bs[1]; leave B(1) in flight ----
  LOAD_A(0);
  WRITE_A(0);                     // compiler auto-waits the A regs
  STAGE_B(0, 0);
  STAGE_B(1, 1);
  asm volatile("s_waitcnt vmcnt(2)" ::: "memory");   // B(0) resident; B(1) in flight
  asm volatile("s_waitcnt lgkmcnt(0)" ::: "memory"); // my ds_writes done
  __builtin_amdgcn_s_barrier();

#pragma unroll 1
  for (int kt = 0; kt < NT; ++kt) {
    const int cA = kt & 1;
    const int cB = kt % 3;
    // phase 0: frags(kk=0) + issue A(kt+1) reg-loads + B(kt+2) staging
    PHASE(cA, cB, 0,
          { if (kt + 1 < NT) LOAD_A(kt + 1); if (kt + 2 < NT) STAGE_B((kt + 2) % 3, kt + 2); });
    __builtin_amdgcn_s_barrier();
    // phase 1: frags(kk=1)
    PHASE(cA, cB, 1, {});
    if (kt + 1 < NT) WRITE_A(cA ^ 1);   // implicit in-order vmem wait retires A(kt+1)+B(kt+1)
    if (kt < NT - 2) asm volatile("s_waitcnt vmcnt(2)" ::: "memory");  // leave B(kt+2) in flight
    else             asm volatile("s_waitcnt vmcnt(0)" ::: "memory");  // tail drain
    asm volatile("s_waitcnt lgkmcnt(0)" ::: "memory");
    __builtin_amdgcn_s_barrier();
  }
#undef STAGE_B
#undef LOAD_A
#undef WRITE_A
#undef PHASE

  // --- epilogue: S[n,m] = acc + c[m] (R7-passed mapping) ---
  const int n0 = brow * 128 + wr * 64 + (lane >> 4) * 4;
  const int m0 = bcol * 128 + wc * 32 + (lane & 15);
#pragma unroll
  for (int j = 0; j < 2; ++j) {
    const float cm = cvec[m0 + j * 16];
#pragma unroll
    for (int i = 0; i < 4; ++i) {
      float* op = out + (size_t)(n0 + i * 16) * Mm + m0 + j * 16;
#pragma unroll
      for (int r = 0; r < 4; ++r)
        op[(size_t)r * Mm] = acc[i][j][r] + cm;
    }
  }
}

extern "C" void kernel_launch(void* const* d_in, const int* in_sizes, int n_in,
                              void* d_out, int out_size, void* d_ws, size_t ws_size,
                              hipStream_t stream) {
  const float* h = (const float*)d_in[0];
  const float* u = (const float*)d_in[1];
  const float* w = (const float*)d_in[2];
  float* out = (float*)d_out;

  // workspace layout: B' bf16 (2MB) | c fp32 (4KB)
  short* Bp  = (short*)d_ws;
  float* cvec = (float*)(Bp + (size_t)Mm * Dd);

  prep_b_kernel<<<Mm, 256, 0, stream>>>(u, w, Bp, cvec);
  gemm_fused_kernel<<<(Nn / 128) * (Mm / 128), 512, 0, stream>>>(h, Bp, cvec, out);
}